// Round 6
// baseline (321.906 us; speedup 1.0000x reference)
//
#include <hip/hip_runtime.h>

#define N_TOK 8192
#define EMB 1024
#define KNOISE 10
#define KP1 11
#define NORM_TERM 9.0f

typedef float f4 __attribute__((ext_vector_type(4)));

// One block per token. Wave w owns EMB-quarter [256w, 256w+256); each lane
// holds one f4 of the input quarter in a register and issues 11 independent
// weight f4 loads (11-deep MLP, pinned by sched_barrier). Last block (ticket)
// does the fixed-order grid reduction — no second kernel.
__global__ __launch_bounds__(256, 2) void nce_fused_kernel(
    const float* __restrict__ input,
    const float* __restrict__ weight,
    const float* __restrict__ bias,
    const float* __restrict__ noise,
    const int* __restrict__ target,
    const int* __restrict__ ns,
    float* __restrict__ token_loss,
    unsigned int* __restrict__ ticket,
    float* __restrict__ out)
{
    __shared__ float s_part[4][12];   // 4 waves x 11 (pad to 12)
    __shared__ int s_last;

    const int n = blockIdx.x;
    const int tid = threadIdx.x;
    const int wave = tid >> 6;
    const int lane = tid & 63;

    int rows[KP1];
    rows[0] = target[n];
    #pragma unroll
    for (int k = 1; k < KP1; ++k)
        rows[k] = ns[n * KNOISE + k - 1];

    const int off = 64 * wave + lane;   // f4 index within the 256-f4 row
    const f4 x4 = reinterpret_cast<const f4*>(input + (size_t)n * EMB)[off];

    // 11 independent gathers — keep ALL loads issued before any consumer.
    f4 w[KP1];
    #pragma unroll
    for (int k = 0; k < KP1; ++k)
        w[k] = reinterpret_cast<const f4*>(weight + (size_t)rows[k] * EMB)[off];
    __builtin_amdgcn_sched_barrier(0);   // don't sink loads into the fma block

    float acc[KP1];
    #pragma unroll
    for (int k = 0; k < KP1; ++k) {
        float a = w[k].x * x4.x;
        a = fmaf(w[k].y, x4.y, a);
        a = fmaf(w[k].z, x4.z, a);
        a = fmaf(w[k].w, x4.w, a);
        acc[k] = a;
    }

    #pragma unroll
    for (int o = 32; o > 0; o >>= 1) {
        #pragma unroll
        for (int k = 0; k < KP1; ++k)
            acc[k] += __shfl_xor(acc[k], o, 64);
    }
    if (lane == 0) {
        #pragma unroll
        for (int k = 0; k < KP1; ++k)
            s_part[wave][k] = acc[k];
    }
    __syncthreads();

    // Wave 0: combine quarters, loss terms, token_loss store, ticket.
    if (wave == 0) {
        float term = 0.f;
        if (lane < KP1) {
            const int row = (lane == 0) ? target[n] : ns[n * KNOISE + lane - 1];
            const float logit = s_part[0][lane] + s_part[1][lane] +
                                s_part[2][lane] + s_part[3][lane] + bias[row];
            const float p = expf(logit - NORM_TERM);
            const float kn = (float)KNOISE * noise[row];
            const float num = (lane == 0) ? p : kn;
            term = logf(num / (p + kn));
        }
        #pragma unroll
        for (int o = 8; o > 0; o >>= 1)
            term += __shfl_xor(term, o, 16);
        if (lane == 0) {
            token_loss[n] = term;
            __threadfence();   // release: token_loss visible before ticket
            const unsigned int old = atomicAdd(ticket, 1u);
            // Exactly one block per call sees residue 8191, for ANY start value.
            s_last = ((old & (unsigned)(N_TOK - 1)) == (unsigned)(N_TOK - 1)) ? 1 : 0;
        }
    }
    __syncthreads();

    if (s_last) {
        __threadfence();   // acquire: see all other blocks' token_loss
        float a = 0.f;
        for (int i = tid; i < N_TOK; i += 256)
            a += token_loss[i];
        #pragma unroll
        for (int o = 32; o > 0; o >>= 1)
            a += __shfl_xor(a, o, 64);
        if (lane == 0) s_part[wave][0] = a;
        __syncthreads();
        if (tid == 0)
            out[0] = -(s_part[0][0] + s_part[1][0] + s_part[2][0] + s_part[3][0])
                     / (float)N_TOK;
    }
}

extern "C" void kernel_launch(void* const* d_in, const int* in_sizes, int n_in,
                              void* d_out, int out_size, void* d_ws, size_t ws_size,
                              hipStream_t stream) {
    const float* input  = (const float*)d_in[0];
    const float* weight = (const float*)d_in[1];
    const float* bias   = (const float*)d_in[2];
    const float* noise  = (const float*)d_in[3];
    const int* target   = (const int*)d_in[4];
    const int* ns       = (const int*)d_in[5];

    float* token_loss    = (float*)d_ws;                        // 32 KB
    unsigned int* ticket = (unsigned int*)((char*)d_ws + 32768);

    nce_fused_kernel<<<N_TOK, 256, 0, stream>>>(
        input, weight, bias, noise, target, ns,
        token_loss, ticket, (float*)d_out);
}

// Round 7
// 66.887 us; speedup vs baseline: 4.8127x; 4.8127x over previous
//
#include <hip/hip_runtime.h>

#define N_TOK 8192
#define EMB 1024
#define KNOISE 10
#define KP1 11
#define NORM_TERM 9.0f

typedef float f4 __attribute__((ext_vector_type(4)));

// One block per token. Wave w owns EMB-quarter [256w, 256w+256); each lane
// holds one f4 of the input quarter in a register and issues 11 independent
// weight f4 loads (11-deep MLP). 11 butterfly reduces -> 4x11 LDS combine ->
// branchless loss terms on wave 0.  (R5 structure, proven 71.6 us.)
__global__ __launch_bounds__(256) void nce_token_kernel(
    const float* __restrict__ input,
    const float* __restrict__ weight,
    const float* __restrict__ bias,
    const float* __restrict__ noise,
    const int* __restrict__ target,
    const int* __restrict__ ns,
    float* __restrict__ token_loss)
{
    __shared__ float s_part[4][12];   // 4 waves x 11 (pad to 12)

    const int n = blockIdx.x;
    const int tid = threadIdx.x;
    const int wave = tid >> 6;
    const int lane = tid & 63;

    // All 11 row indices (compile-time-indexed register array).
    int rows[KP1];
    rows[0] = target[n];
    #pragma unroll
    for (int k = 1; k < KP1; ++k)
        rows[k] = ns[n * KNOISE + k - 1];

    const int off = 64 * wave + lane;   // f4 index within the 256-f4 row
    const f4 x4 = reinterpret_cast<const f4*>(input + (size_t)n * EMB)[off];

    // 11 independent gathers — maximize loads in flight.
    f4 w[KP1];
    #pragma unroll
    for (int k = 0; k < KP1; ++k)
        w[k] = reinterpret_cast<const f4*>(weight + (size_t)rows[k] * EMB)[off];

    float acc[KP1];
    #pragma unroll
    for (int k = 0; k < KP1; ++k) {
        float a = w[k].x * x4.x;
        a = fmaf(w[k].y, x4.y, a);
        a = fmaf(w[k].z, x4.z, a);
        a = fmaf(w[k].w, x4.w, a);
        acc[k] = a;
    }

    // Butterfly-reduce each of the 11 partial dots across the wave.
    #pragma unroll
    for (int o = 32; o > 0; o >>= 1) {
        #pragma unroll
        for (int k = 0; k < KP1; ++k)
            acc[k] += __shfl_xor(acc[k], o, 64);
    }
    if (lane == 0) {
        #pragma unroll
        for (int k = 0; k < KP1; ++k)
            s_part[wave][k] = acc[k];
    }
    __syncthreads();

    // Wave 0, lanes 0..10: combine quarters, compute loss term (branchless).
    if (wave == 0) {
        float term = 0.f;
        if (lane < KP1) {
            const int row = (lane == 0) ? target[n] : ns[n * KNOISE + lane - 1];
            const float logit = s_part[0][lane] + s_part[1][lane] +
                                s_part[2][lane] + s_part[3][lane] + bias[row];
            const float p = expf(logit - NORM_TERM);
            const float kn = (float)KNOISE * noise[row];
            const float num = (lane == 0) ? p : kn;
            term = logf(num / (p + kn));
        }
        #pragma unroll
        for (int o = 8; o > 0; o >>= 1)
            term += __shfl_xor(term, o, 16);
        if (lane == 0) token_loss[n] = term;
    }
}

// Single-block reduction, f4-vectorized: 2048 f4 over 256 threads = 8
// independent 16B loads per thread (one latency exposure, not 32).
__global__ __launch_bounds__(256) void nce_reduce_kernel(
    const float* __restrict__ token_loss, float* __restrict__ out)
{
    __shared__ float s_part[4];
    const f4* tl4 = reinterpret_cast<const f4*>(token_loss);
    float acc = 0.f;
    #pragma unroll
    for (int i = 0; i < 8; ++i) {
        const f4 v = tl4[threadIdx.x + 256 * i];
        acc += (v.x + v.y) + (v.z + v.w);
    }
    #pragma unroll
    for (int off = 32; off > 0; off >>= 1)
        acc += __shfl_xor(acc, off, 64);
    const int wave = threadIdx.x >> 6;
    const int lane = threadIdx.x & 63;
    if (lane == 0) s_part[wave] = acc;
    __syncthreads();
    if (threadIdx.x == 0) {
        const float total = (s_part[0] + s_part[1]) + (s_part[2] + s_part[3]);
        out[0] = -total / (float)N_TOK;
    }
}

extern "C" void kernel_launch(void* const* d_in, const int* in_sizes, int n_in,
                              void* d_out, int out_size, void* d_ws, size_t ws_size,
                              hipStream_t stream) {
    const float* input  = (const float*)d_in[0];
    const float* weight = (const float*)d_in[1];
    const float* bias   = (const float*)d_in[2];
    const float* noise  = (const float*)d_in[3];
    const int* target   = (const int*)d_in[4];
    const int* ns       = (const int*)d_in[5];

    float* token_loss = (float*)d_ws;   // 32 KB scratch

    nce_token_kernel<<<N_TOK, 256, 0, stream>>>(
        input, weight, bias, noise, target, ns, token_loss);
    nce_reduce_kernel<<<1, 256, 0, stream>>>(token_loss, (float*)d_out);
}